// Round 6
// baseline (18046.167 us; speedup 1.0000x reference)
//
#include <hip/hip_runtime.h>
#include <cstddef>
#include <cstdint>

using f32x4  = __attribute__((ext_vector_type(4))) float;
using bf16x8 = __attribute__((ext_vector_type(8))) short;
using u16x4  = __attribute__((ext_vector_type(4))) unsigned short;
typedef unsigned short u16;

#define LMDA 0.005f

__device__ __forceinline__ u16 f2bf(float f) {
    union { float f; uint32_t u; } v; v.f = f;
    return (u16)((v.u + 0x7FFFu + ((v.u >> 16) & 1u)) >> 16);
}
__device__ __forceinline__ float bf2f(u16 b) {
    union { uint32_t u; float f; } v; v.u = ((uint32_t)b) << 16;
    return v.f;
}
__device__ __forceinline__ void split2(float x, u16& h, u16& l) {
    h = f2bf(x); l = f2bf(x - bf2f(h));
}
__device__ __forceinline__ float sthr(float x) {
    float ax = fabsf(x) - LMDA;
    return ax > 0.0f ? copysignf(ax, x) : 0.0f;
}

// async 16B global -> LDS (HW writes lane l at ldsbase + l*16)
__device__ __forceinline__ void gload16(const u16* g, u16* l) {
    __builtin_amdgcn_global_load_lds(
        (const __attribute__((address_space(1))) unsigned int*)(const void*)g,
        (__attribute__((address_space(3))) unsigned int*)(void*)l, 16, 0, 0);
}

// ---------------------------------------------------------------------------
// PROLOGUE GEMM (unchanged from round 5, passing): fused-3 split-bf16 NT GEMM.
// Used only for W = I - 0.2*U@U^T (EPI 2) and Csc = 0.2*img@U^T (EPI 1).
// ---------------------------------------------------------------------------
template<int EPI>
__global__ __launch_bounds__(512, 2)
void gemm_ista(const u16* __restrict__ Ah, const u16* __restrict__ Al,
               const u16* __restrict__ Bh, const u16* __restrict__ Bl,
               int Nt,
               const float* __restrict__ Cs, float* __restrict__ OutF,
               u16* __restrict__ OutH, u16* __restrict__ OutL)
{
    __shared__ __align__(16) u16 S[3][48 * 512];   // 144 KiB

    const int nwg = gridDim.x;
    const int fid = blockIdx.x;
    const int sid = (fid & 7) * (nwg >> 3) + (fid >> 3);
    const int row0 = (sid / Nt) << 7;
    const int col0 = (sid % Nt) << 6;

    const int tid  = threadIdx.x;
    const int lane = tid & 63;
    const int w    = tid >> 6;      // 0..7
    const int mr = w >> 2, nc = (w >> 1) & 1, ks = w & 1;

    const u16* gb[6];
    int cf[6];
    #pragma unroll
    for (int t = 0; t < 6; ++t) {
        const int c = w * 6 + t;
        const u16* base; int r; int kss;
        if (c < 32) {
            const int h = (c >> 4) & 1; kss = (c >> 3) & 1;
            base = h ? Al : Ah;
            r = row0 + ((c & 7) << 4) + (lane & 15);
        } else {
            const int cb = c - 32;
            const int h = (cb >> 3) & 1; kss = (cb >> 2) & 1;
            base = h ? Bl : Bh;
            r = col0 + ((cb & 3) << 4) + (lane & 15);
        }
        gb[t] = base + ((size_t)r << 10) + (kss << 5) + ((lane >> 4) << 3);
        cf[t] = c << 9;
    }
    auto stage = [&](int b, int koff) {
        #pragma unroll
        for (int t = 0; t < 6; ++t)
            gload16(gb[t] + koff, &S[b][cf[t]]);
    };

    f32x4 acc[4][2] = {};

    stage(0, 0);
    stage(1, 64);

    #pragma unroll
    for (int s = 0; s < 16; ++s) {
        if (s <= 14) asm volatile("s_waitcnt vmcnt(6)" ::: "memory");
        else         asm volatile("s_waitcnt vmcnt(0)" ::: "memory");
        __builtin_amdgcn_s_barrier();
        asm volatile("" ::: "memory");
        if (s + 2 < 16) stage((s + 2) % 3, (s + 2) << 6);

        const u16* Sb = S[s % 3];
        const int ab = (ks << 3) + (mr << 2);
        const int bb = 32 + (ks << 2) + (nc << 1);
        bf16x8 ah[4], al[4], bh[2], bl[2];
        #pragma unroll
        for (int i = 0; i < 4; ++i) {
            ah[i] = *(const bf16x8*)&Sb[(ab + i)      * 512 + (lane << 3)];
            al[i] = *(const bf16x8*)&Sb[(ab + 16 + i) * 512 + (lane << 3)];
        }
        #pragma unroll
        for (int j = 0; j < 2; ++j) {
            bh[j] = *(const bf16x8*)&Sb[(bb + j)     * 512 + (lane << 3)];
            bl[j] = *(const bf16x8*)&Sb[(bb + 8 + j) * 512 + (lane << 3)];
        }
        #pragma unroll
        for (int i = 0; i < 4; ++i)
            #pragma unroll
            for (int j = 0; j < 2; ++j)
                acc[i][j] = __builtin_amdgcn_mfma_f32_16x16x32_bf16(ah[i], bh[j], acc[i][j], 0, 0, 0);
        #pragma unroll
        for (int i = 0; i < 4; ++i)
            #pragma unroll
            for (int j = 0; j < 2; ++j)
                acc[i][j] = __builtin_amdgcn_mfma_f32_16x16x32_bf16(al[i], bh[j], acc[i][j], 0, 0, 0);
        #pragma unroll
        for (int i = 0; i < 4; ++i)
            #pragma unroll
            for (int j = 0; j < 2; ++j)
                acc[i][j] = __builtin_amdgcn_mfma_f32_16x16x32_bf16(ah[i], bl[j], acc[i][j], 0, 0, 0);
        asm volatile("" ::: "memory");
    }

    __syncthreads();
    f32x4* red = (f32x4*)&S[0][0];
    const int wquad = (mr << 1) + nc;
    #pragma unroll
    for (int ih = 0; ih < 2; ++ih) {
        #pragma unroll
        for (int j = 0; j < 2; ++j) {
            const int isrc = ks ? ih : (2 + ih);
            const int slot = ((((wquad << 1) | ks) << 2) | (ih << 1) | j);
            red[slot * 64 + lane] = acc[isrc][j];
        }
    }
    __syncthreads();

    const int gr0 = row0 + (mr << 6) + ((lane >> 4) << 2);
    const int gc  = col0 + (nc << 5) + (lane & 15);
    #pragma unroll
    for (int ih = 0; ih < 2; ++ih) {
        #pragma unroll
        for (int j = 0; j < 2; ++j) {
            const int i    = ks ? (2 + ih) : ih;
            const int slot = ((((wquad << 1) | (ks ^ 1)) << 2) | (ih << 1) | j);
            f32x4 sum = acc[i][j] + red[slot * 64 + lane];
            #pragma unroll
            for (int e = 0; e < 4; ++e) {
                const int grow = gr0 + (i << 4) + e;
                const int gcol = gc + (j << 4);
                const size_t idx = ((size_t)grow << 10) + gcol;
                const float p = sum[e];
                if (EPI == 1) {
                    float f = 0.2f * p;
                    OutF[idx] = f;
                    u16 h, l; split2(sthr(f), h, l);
                    OutH[idx] = h; OutL[idx] = l;
                } else {
                    float x = (grow == gcol ? 1.0f : 0.0f) - 0.2f * p;
                    u16 h, l; split2(x, h, l);
                    OutH[idx] = h; OutL[idx] = l;
                }
            }
        }
    }
}

// ---------------------------------------------------------------------------
// PERSISTENT ISTA kernel: 64 blocks x 32 rows, all 150 iterations + final out.
// R lives in LDS as bf16 (hi,lo) pair, XOR-swizzled (both sides manual).
// Per iteration: acc init = Csc (MFMA C-in), K-loop streams W from L2 with
// swapped operands mfma(W-frag, R-frag): D rows = n-dim -> e spans 4
// consecutive n => ds_write_b64 R-update, dwordx4 Csc/out access.
// 3 products: Wh*Rh + Wl*Rh + Wh*Rl  ==  Rh*Wh + Rh*Wl + Rl*Wh.
// 2 barriers per iteration. Blocks fully independent (row decomposition).
// ---------------------------------------------------------------------------
__global__ __launch_bounds__(512, 2)
void pc_iter(const u16* __restrict__ Wh, const u16* __restrict__ Wl,
             const u16* __restrict__ Uth, const u16* __restrict__ Utl,
             const float* __restrict__ Csc, float* __restrict__ out)
{
    __shared__ __align__(16) u16 Rh[32 * 1024];   // 64 KiB
    __shared__ __align__(16) u16 Rl[32 * 1024];   // 64 KiB

    const int r0g  = blockIdx.x << 5;             // rows [r0g, r0g+32)
    const int tid  = threadIdx.x;
    const int lane = tid & 63;
    const int w    = tid >> 6;                    // 0..7, n-slab [w*128, +128)
    const int l15  = lane & 15;
    const int lg   = lane >> 4;                   // 0..3

    // per-lane element offset for P-frag loads: P[(w*128 + ni*16 + l15)][lg*8..]
    const size_t lb = ((size_t)((w << 7) + l15) << 10) + (size_t)(lg << 3);

    // swizzled LDS offset for R[row][k]: granule(k>>3) ^= row&7 (bijective/row)
    auto rswz = [&](int row, int k) {
        return (row << 10) + ((((k >> 3) ^ (row & 7)) << 3) | (k & 7));
    };
    // global fp32 offset for frag (ni,mj): row=r0g+mj*16+l15, col=w*128+ni*16+lg*4
    auto gidx = [&](int ni, int mj) {
        return ((size_t)(r0g + (mj << 4) + l15) << 10) + (size_t)((w << 7) + (ni << 4) + (lg << 2));
    };

    f32x4 acc[8][2];

    auto load_c = [&]() {
        #pragma unroll
        for (int ni = 0; ni < 8; ++ni)
            #pragma unroll
            for (int mj = 0; mj < 2; ++mj)
                acc[ni][mj] = *(const f32x4*)&Csc[gidx(ni, mj)];
    };

    auto kloop = [&](const u16* __restrict__ Ph, const u16* __restrict__ Pl) {
        #pragma unroll 4
        for (int s = 0; s < 32; ++s) {
            const int k0 = s << 5;
            bf16x8 rh[2], rl[2];
            #pragma unroll
            for (int mj = 0; mj < 2; ++mj) {
                const int ro = rswz((mj << 4) + l15, k0 + (lg << 3));
                rh[mj] = *(const bf16x8*)&Rh[ro];
                rl[mj] = *(const bf16x8*)&Rl[ro];
            }
            bf16x8 wh[8], wl[8];
            #pragma unroll
            for (int ni = 0; ni < 8; ++ni) {
                wh[ni] = *(const bf16x8*)(Ph + lb + (ni << 14) + k0);
                wl[ni] = *(const bf16x8*)(Pl + lb + (ni << 14) + k0);
            }
            #pragma unroll
            for (int ni = 0; ni < 8; ++ni)
                #pragma unroll
                for (int mj = 0; mj < 2; ++mj) {
                    acc[ni][mj] = __builtin_amdgcn_mfma_f32_16x16x32_bf16(wh[ni], rh[mj], acc[ni][mj], 0, 0, 0);
                    acc[ni][mj] = __builtin_amdgcn_mfma_f32_16x16x32_bf16(wl[ni], rh[mj], acc[ni][mj], 0, 0, 0);
                    acc[ni][mj] = __builtin_amdgcn_mfma_f32_16x16x32_bf16(wh[ni], rl[mj], acc[ni][mj], 0, 0, 0);
                }
        }
    };

    auto store_r = [&]() {
        #pragma unroll
        for (int ni = 0; ni < 8; ++ni)
            #pragma unroll
            for (int mj = 0; mj < 2; ++mj) {
                u16x4 hv, lv;
                #pragma unroll
                for (int e = 0; e < 4; ++e) {
                    u16 hh, ll; split2(sthr(acc[ni][mj][e]), hh, ll);
                    hv[e] = hh; lv[e] = ll;
                }
                const int ro = rswz((mj << 4) + l15, (w << 7) + (ni << 4) + (lg << 2));
                *(u16x4*)&Rh[ro] = hv;
                *(u16x4*)&Rl[ro] = lv;
            }
    };

    // iteration 1: R1 = st(Csc)   (R0 = 0 -> no matmul)
    load_c();
    store_r();
    __syncthreads();

    // iterations 2..150: R <- st(R @ W + Csc)
    for (int it = 0; it < 149; ++it) {
        load_c();
        kloop(Wh, Wl);
        __syncthreads();     // everyone done reading R
        store_r();
        __syncthreads();     // new R visible
    }

    // final: out = R @ U  (NT against Ut)
    #pragma unroll
    for (int ni = 0; ni < 8; ++ni)
        #pragma unroll
        for (int mj = 0; mj < 2; ++mj)
            acc[ni][mj] = f32x4{0.0f, 0.0f, 0.0f, 0.0f};
    kloop(Uth, Utl);
    #pragma unroll
    for (int ni = 0; ni < 8; ++ni)
        #pragma unroll
        for (int mj = 0; mj < 2; ++mj)
            *(f32x4*)&out[gidx(ni, mj)] = acc[ni][mj];
}

// fp32 -> (hi, lo) bf16 pair, elementwise
__global__ void k_split(const float* __restrict__ in, u16* __restrict__ hi,
                        u16* __restrict__ lo, int n)
{
    int i = blockIdx.x * 256 + threadIdx.x;
    if (i < n) { u16 h, l; split2(in[i], h, l); hi[i] = h; lo[i] = l; }
}

// Ut[j][k] = U[k][j] as bf16 pair (32x32 LDS tile, padded)
__global__ __launch_bounds__(256)
void k_transpose_split(const float* __restrict__ in, u16* __restrict__ hi,
                       u16* __restrict__ lo)
{
    __shared__ float t[32][33];
    const int bx = blockIdx.x, by = blockIdx.y;
    const int lx = threadIdx.x & 31, ly = threadIdx.x >> 5;
    #pragma unroll
    for (int rr = 0; rr < 4; ++rr) {
        int r = ly * 4 + rr;
        t[r][lx] = in[(size_t)(by * 32 + r) * 1024 + bx * 32 + lx];
    }
    __syncthreads();
    #pragma unroll
    for (int rr = 0; rr < 4; ++rr) {
        int r = ly * 4 + rr;
        u16 h, l; split2(t[lx][r], h, l);
        size_t idx = (size_t)(bx * 32 + r) * 1024 + by * 32 + lx;
        hi[idx] = h; lo[idx] = l;
    }
}

extern "C" void kernel_launch(void* const* d_in, const int* in_sizes, int n_in,
                              void* d_out, int out_size, void* d_ws, size_t ws_size,
                              hipStream_t stream) {
    const float* img = (const float*)d_in[0];   // (2048, 1024) fp32
    const float* U   = (const float*)d_in[1];   // (1024, 1024) fp32
    float* out = (float*)d_out;                 // (2048, 1024) fp32

    char* ws = (char*)d_ws;
    auto MB = [](size_t m) { return m << 20; };
    u16*   Uh  = (u16*)(ws + MB(0));
    u16*   Ul  = (u16*)(ws + MB(2));
    u16*   Uth = (u16*)(ws + MB(4));
    u16*   Utl = (u16*)(ws + MB(6));
    u16*   Wh  = (u16*)(ws + MB(8));
    u16*   Wl  = (u16*)(ws + MB(10));
    float* Csc = (float*)(ws + MB(12));          // 8 MB
    u16*   Rah = (u16*)(ws + MB(20));            // dead stores from EPI 1
    u16*   Ral = (u16*)(ws + MB(24));
    u16*   Ih  = (u16*)(ws + MB(28));            // img split (prologue only)
    u16*   Il  = (u16*)(ws + MB(32));            // ends at 36 MB

    // ---- prologue ----
    k_split<<<4096, 256, 0, stream>>>(U, Uh, Ul, 1024 * 1024);
    k_split<<<8192, 256, 0, stream>>>(img, Ih, Il, 2048 * 1024);
    k_transpose_split<<<dim3(32, 32), 256, 0, stream>>>(U, Uth, Utl);

    // W = I - 0.2 * U @ U^T   (8x16 = 128 blocks)
    gemm_ista<2><<<128, 512, 0, stream>>>(Uh, Ul, Uh, Ul, 16,
                                          nullptr, nullptr, Wh, Wl);

    // Csc = 0.2 * img @ U^T   (16x16 = 256 blocks)
    gemm_ista<1><<<256, 512, 0, stream>>>(Ih, Il, Uh, Ul, 16,
                                          nullptr, Csc, Rah, Ral);

    // ---- persistent: all 150 ISTA iterations + final out = R@U ----
    pc_iter<<<64, 512, 0, stream>>>(Wh, Wl, Uth, Utl, Csc, out);
}

// Round 7
// 9379.518 us; speedup vs baseline: 1.9240x; 1.9240x over previous
//
#include <hip/hip_runtime.h>
#include <cstddef>
#include <cstdint>

using f32x4  = __attribute__((ext_vector_type(4))) float;
using bf16x8 = __attribute__((ext_vector_type(8))) short;
using u16x4  = __attribute__((ext_vector_type(4))) unsigned short;
typedef unsigned short u16;
typedef unsigned int   u32;

#define LMDA 0.005f

__device__ __forceinline__ u16 f2bf(float f) {
    union { float f; uint32_t u; } v; v.f = f;
    return (u16)((v.u + 0x7FFFu + ((v.u >> 16) & 1u)) >> 16);
}
__device__ __forceinline__ float bf2f(u16 b) {
    union { uint32_t u; float f; } v; v.u = ((uint32_t)b) << 16;
    return v.f;
}
__device__ __forceinline__ void split2(float x, u16& h, u16& l) {
    h = f2bf(x); l = f2bf(x - bf2f(h));
}
__device__ __forceinline__ float sthr(float x) {
    float ax = fabsf(x) - LMDA;
    return ax > 0.0f ? copysignf(ax, x) : 0.0f;
}

// async 16B global -> LDS (HW writes lane l at ldsbase + l*16)
__device__ __forceinline__ void gload16(const u16* g, u16* l) {
    __builtin_amdgcn_global_load_lds(
        (const __attribute__((address_space(1))) unsigned int*)(const void*)g,
        (__attribute__((address_space(3))) unsigned int*)(void*)l, 16, 0, 0);
}

// ---------------------------------------------------------------------------
// PER-ITERATION GEMM, tile 128x128, split-K 4, fused flag-based combine.
//   acc[n][m] = sum_{k in chunk} (Wh*Rh + Wl*Rh + Wh*Rl)   [swapped operands:
//   mfma(A=W-frag(n,k), B=R-frag(m,k)) -> D row-axis (4-elem regs) = n]
// grid 512 = (tr*4 + c)*8 + tn :  tr 0..15 row-tile, tn 0..7 col-tile, c 0..3
// k-chunk (256 wide). 256 thr = 4 waves (wr,wc), wave-tile 64x64.
// K-loop: 8 steps of BK=32, LDS 2 x 32KB fragment-ordered (lane*16B),
// global_load_lds staging, vmcnt(0)+barrier at step top (prefetch depth 1).
// Epilogue: chunks c != comb store flat fp32 partials -> release atomicAdd;
// chunk c == comb spins acquire (==3), sums 3 partials + own acc, then:
//   OM 0: x = sum + Csc; R' = split(soft_threshold(x))  (ISTA step)
//   OM 1: OutF = sum                                    (final out = R@U)
// ---------------------------------------------------------------------------
template<int OM>
__global__ __launch_bounds__(256, 2)
void gemm_it(const u16* __restrict__ Ah, const u16* __restrict__ Al,   // W or Ut
             const u16* __restrict__ Rh, const u16* __restrict__ Rl,   // current R
             const float* __restrict__ Cs,
             u16* __restrict__ Nh, u16* __restrict__ Nl,               // next R
             float* __restrict__ OutF,
             float* __restrict__ P, u32* __restrict__ ready, int comb)
{
    __shared__ __align__(16) u16 S[2 * 32 * 512];   // 64 KiB

    const int bid = blockIdx.x;
    const int tn  = bid & 7;
    const int g   = bid >> 3;
    const int tr  = g >> 2;
    const int c   = g & 3;
    const int tile = tr * 8 + tn;
    const int row0 = tr << 7;       // R rows
    const int col0 = tn << 7;       // n cols
    const int kbase = c << 8;       // k-chunk origin

    const int tid  = threadIdx.x;
    const int lane = tid & 63;
    const int w    = tid >> 6;      // 0..3
    const int wr   = w >> 1;        // m-half
    const int wc   = w & 1;         // n-half
    const int l15  = lane & 15;
    const int lg   = lane >> 4;     // 0..3
    const int l8   = lane << 3;     // u16 idx of lane's 16B

    // ---- staging roles: 32 chunks of 1KB (16 W + 16 R), 8 per wave ----
    // W chunk q in [0,16): h=q>>3, ci=q&7 : lane <- W[col0+ci*16+l15][k + lg*8]
    // R chunk q in [16,32): h, mi          : lane <- R[row0+mi*16+l15][k + lg*8]
    const u16* gsrc[8];
    int loff[8];
    #pragma unroll
    for (int t = 0; t < 8; ++t) {
        const int q = (w << 3) + t;
        const u16* base; int r;
        if (q < 16) {
            base = (q >> 3) ? Al : Ah;
            r = col0 + ((q & 7) << 4) + l15;
        } else {
            const int q2 = q - 16;
            base = (q2 >> 3) ? Rl : Rh;
            r = row0 + ((q2 & 7) << 4) + l15;
        }
        gsrc[t] = base + ((size_t)r << 10) + (lg << 3);
        loff[t] = (q << 9) + l8;
    }
    auto stage = [&](int b, int k) {
        #pragma unroll
        for (int t = 0; t < 8; ++t)
            gload16(gsrc[t] + k, &S[(b << 14) + loff[t]]);
    };

    f32x4 acc[4][4] = {};   // [ni][mj]

    stage(0, kbase);

    for (int s = 0; s < 8; ++s) {
        asm volatile("s_waitcnt vmcnt(0)" ::: "memory");
        __builtin_amdgcn_s_barrier();
        asm volatile("" ::: "memory");
        if (s < 7) stage((s + 1) & 1, kbase + ((s + 1) << 5));

        const int bo = (s & 1) << 14;
        bf16x8 wh[4], wl[4], rh[4], rl[4];
        #pragma unroll
        for (int i = 0; i < 4; ++i) {
            const int ci = (wc << 2) + i;
            const int mi = (wr << 2) + i;
            wh[i] = *(const bf16x8*)&S[bo + ((0  + ci) << 9) + l8];
            wl[i] = *(const bf16x8*)&S[bo + ((8  + ci) << 9) + l8];
            rh[i] = *(const bf16x8*)&S[bo + ((16 + mi) << 9) + l8];
            rl[i] = *(const bf16x8*)&S[bo + ((24 + mi) << 9) + l8];
        }
        #pragma unroll
        for (int ni = 0; ni < 4; ++ni)
            #pragma unroll
            for (int mj = 0; mj < 4; ++mj) {
                acc[ni][mj] = __builtin_amdgcn_mfma_f32_16x16x32_bf16(wh[ni], rh[mj], acc[ni][mj], 0, 0, 0);
                acc[ni][mj] = __builtin_amdgcn_mfma_f32_16x16x32_bf16(wl[ni], rh[mj], acc[ni][mj], 0, 0, 0);
                acc[ni][mj] = __builtin_amdgcn_mfma_f32_16x16x32_bf16(wh[ni], rl[mj], acc[ni][mj], 0, 0, 0);
            }
        asm volatile("" ::: "memory");
    }

    // ---- epilogue: fused split-K combine via agent-scope flags ----
    if (c != comb) {
        const int slot = c - (c > comb ? 1 : 0);           // 0..2
        const size_t pb = ((size_t)tile * 3 + slot) * 16384;
        #pragma unroll
        for (int f = 0; f < 16; ++f)
            *(f32x4*)&P[pb + (f << 10) + (tid << 2)] = acc[f >> 2][f & 3];
        __syncthreads();
        if (tid == 0)
            __hip_atomic_fetch_add(ready + tile, 1u, __ATOMIC_RELEASE,
                                   __HIP_MEMORY_SCOPE_AGENT);
        return;
    }

    if (tid == 0) {
        int guard = 0;
        while (__hip_atomic_load(ready + tile, __ATOMIC_ACQUIRE,
                                 __HIP_MEMORY_SCOPE_AGENT) < 3u &&
               ++guard < (1 << 22))
            __builtin_amdgcn_s_sleep(1);
    }
    __syncthreads();

    const size_t pb0 = (size_t)tile * 3 * 16384;
    #pragma unroll
    for (int ni = 0; ni < 4; ++ni) {
        #pragma unroll
        for (int mj = 0; mj < 4; ++mj) {
            const int f = (ni << 2) + mj;
            f32x4 sum = acc[ni][mj];
            #pragma unroll
            for (int sl = 0; sl < 3; ++sl)
                sum += *(const f32x4*)&P[pb0 + (size_t)sl * 16384 + (f << 10) + (tid << 2)];

            // D layout: col(lane&15)=m-local, row((lane>>4)*4+e)=n-local
            const int m  = row0 + (wr << 6) + (mj << 4) + l15;
            const int n0 = col0 + (wc << 6) + (ni << 4) + (lg << 2);
            const size_t idx = ((size_t)m << 10) + n0;
            if (OM == 0) {
                const f32x4 cs = *(const f32x4*)&Cs[idx];
                u16x4 hv, lv;
                #pragma unroll
                for (int e = 0; e < 4; ++e) {
                    u16 hh, ll; split2(sthr(sum[e] + cs[e]), hh, ll);
                    hv[e] = hh; lv[e] = ll;
                }
                *(u16x4*)&Nh[idx] = hv;
                *(u16x4*)&Nl[idx] = lv;
            } else {
                *(f32x4*)&OutF[idx] = sum;
            }
        }
    }
}

// ---------------------------------------------------------------------------
// PROLOGUE GEMM (round-5, passing): fused-3 split-bf16 NT GEMM + epilogues.
// EPI 0: OutF = acc ; EPI 1: OutF=0.2acc + R=split(st(.)) ; EPI 2: W ;
// EPI 3: R' = split(st(acc + Cs))   (EPI 0/3 used by the fallback path)
// ---------------------------------------------------------------------------
template<int EPI>
__global__ __launch_bounds__(512, 2)
void gemm_ista(const u16* __restrict__ Ah, const u16* __restrict__ Al,
               const u16* __restrict__ Bh, const u16* __restrict__ Bl,
               int Nt,
               const float* __restrict__ Cs, float* __restrict__ OutF,
               u16* __restrict__ OutH, u16* __restrict__ OutL)
{
    __shared__ __align__(16) u16 S[3][48 * 512];   // 144 KiB

    const int nwg = gridDim.x;
    const int fid = blockIdx.x;
    const int sid = (fid & 7) * (nwg >> 3) + (fid >> 3);
    const int row0 = (sid / Nt) << 7;
    const int col0 = (sid % Nt) << 6;

    const int tid  = threadIdx.x;
    const int lane = tid & 63;
    const int w    = tid >> 6;
    const int mr = w >> 2, nc = (w >> 1) & 1, ks = w & 1;

    const u16* gb[6];
    int cf[6];
    #pragma unroll
    for (int t = 0; t < 6; ++t) {
        const int c = w * 6 + t;
        const u16* base; int r; int kss;
        if (c < 32) {
            const int h = (c >> 4) & 1; kss = (c >> 3) & 1;
            base = h ? Al : Ah;
            r = row0 + ((c & 7) << 4) + (lane & 15);
        } else {
            const int cb = c - 32;
            const int h = (cb >> 3) & 1; kss = (cb >> 2) & 1;
            base = h ? Bl : Bh;
            r = col0 + ((cb & 3) << 4) + (lane & 15);
        }
        gb[t] = base + ((size_t)r << 10) + (kss << 5) + ((lane >> 4) << 3);
        cf[t] = c << 9;
    }
    auto stage = [&](int b, int koff) {
        #pragma unroll
        for (int t = 0; t < 6; ++t)
            gload16(gb[t] + koff, &S[b][cf[t]]);
    };

    f32x4 acc[4][2] = {};

    stage(0, 0);
    stage(1, 64);

    #pragma unroll
    for (int s = 0; s < 16; ++s) {
        if (s <= 14) asm volatile("s_waitcnt vmcnt(6)" ::: "memory");
        else         asm volatile("s_waitcnt vmcnt(0)" ::: "memory");
        __builtin_amdgcn_s_barrier();
        asm volatile("" ::: "memory");
        if (s + 2 < 16) stage((s + 2) % 3, (s + 2) << 6);

        const u16* Sb = S[s % 3];
        const int ab = (ks << 3) + (mr << 2);
        const int bb = 32 + (ks << 2) + (nc << 1);
        bf16x8 ah[4], al[4], bh[2], bl[2];
        #pragma unroll
        for (int i = 0; i < 4; ++i) {
            ah[i] = *(const bf16x8*)&Sb[(ab + i)      * 512 + (lane << 3)];
            al[i] = *(const bf16x8*)&Sb[(ab + 16 + i) * 512 + (lane << 3)];
        }
        #pragma unroll
        for (int j = 0; j < 2; ++j) {
            bh[j] = *(const bf16x8*)&Sb[(bb + j)     * 512 + (lane << 3)];
            bl[j] = *(const bf16x8*)&Sb[(bb + 8 + j) * 512 + (lane << 3)];
        }
        #pragma unroll
        for (int i = 0; i < 4; ++i)
            #pragma unroll
            for (int j = 0; j < 2; ++j)
                acc[i][j] = __builtin_amdgcn_mfma_f32_16x16x32_bf16(ah[i], bh[j], acc[i][j], 0, 0, 0);
        #pragma unroll
        for (int i = 0; i < 4; ++i)
            #pragma unroll
            for (int j = 0; j < 2; ++j)
                acc[i][j] = __builtin_amdgcn_mfma_f32_16x16x32_bf16(al[i], bh[j], acc[i][j], 0, 0, 0);
        #pragma unroll
        for (int i = 0; i < 4; ++i)
            #pragma unroll
            for (int j = 0; j < 2; ++j)
                acc[i][j] = __builtin_amdgcn_mfma_f32_16x16x32_bf16(ah[i], bl[j], acc[i][j], 0, 0, 0);
        asm volatile("" ::: "memory");
    }

    __syncthreads();
    f32x4* red = (f32x4*)&S[0][0];
    const int wquad = (mr << 1) + nc;
    #pragma unroll
    for (int ih = 0; ih < 2; ++ih) {
        #pragma unroll
        for (int j = 0; j < 2; ++j) {
            const int isrc = ks ? ih : (2 + ih);
            const int slot = ((((wquad << 1) | ks) << 2) | (ih << 1) | j);
            red[slot * 64 + lane] = acc[isrc][j];
        }
    }
    __syncthreads();

    const int gr0 = row0 + (mr << 6) + ((lane >> 4) << 2);
    const int gc  = col0 + (nc << 5) + (lane & 15);
    #pragma unroll
    for (int ih = 0; ih < 2; ++ih) {
        #pragma unroll
        for (int j = 0; j < 2; ++j) {
            const int i    = ks ? (2 + ih) : ih;
            const int slot = ((((wquad << 1) | (ks ^ 1)) << 2) | (ih << 1) | j);
            f32x4 sum = acc[i][j] + red[slot * 64 + lane];
            #pragma unroll
            for (int e = 0; e < 4; ++e) {
                const int grow = gr0 + (i << 4) + e;
                const int gcol = gc + (j << 4);
                const size_t idx = ((size_t)grow << 10) + gcol;
                const float p = sum[e];
                if (EPI == 0) {
                    OutF[idx] = p;
                } else if (EPI == 1) {
                    float f = 0.2f * p;
                    OutF[idx] = f;
                    u16 h, l; split2(sthr(f), h, l);
                    OutH[idx] = h; OutL[idx] = l;
                } else if (EPI == 2) {
                    float x = (grow == gcol ? 1.0f : 0.0f) - 0.2f * p;
                    u16 h, l; split2(x, h, l);
                    OutH[idx] = h; OutL[idx] = l;
                } else {
                    float x = p + Cs[idx];
                    u16 h, l; split2(sthr(x), h, l);
                    OutH[idx] = h; OutL[idx] = l;
                }
            }
        }
    }
}

// fp32 -> (hi, lo) bf16 pair, elementwise
__global__ void k_split(const float* __restrict__ in, u16* __restrict__ hi,
                        u16* __restrict__ lo, int n)
{
    int i = blockIdx.x * 256 + threadIdx.x;
    if (i < n) { u16 h, l; split2(in[i], h, l); hi[i] = h; lo[i] = l; }
}

// Ut[j][k] = U[k][j] as bf16 pair (32x32 LDS tile, padded)
__global__ __launch_bounds__(256)
void k_transpose_split(const float* __restrict__ in, u16* __restrict__ hi,
                       u16* __restrict__ lo)
{
    __shared__ float t[32][33];
    const int bx = blockIdx.x, by = blockIdx.y;
    const int lx = threadIdx.x & 31, ly = threadIdx.x >> 5;
    #pragma unroll
    for (int rr = 0; rr < 4; ++rr) {
        int r = ly * 4 + rr;
        t[r][lx] = in[(size_t)(by * 32 + r) * 1024 + bx * 32 + lx];
    }
    __syncthreads();
    #pragma unroll
    for (int rr = 0; rr < 4; ++rr) {
        int r = ly * 4 + rr;
        u16 h, l; split2(t[lx][r], h, l);
        size_t idx = (size_t)(bx * 32 + r) * 1024 + by * 32 + lx;
        hi[idx] = h; lo[idx] = l;
    }
}

extern "C" void kernel_launch(void* const* d_in, const int* in_sizes, int n_in,
                              void* d_out, int out_size, void* d_ws, size_t ws_size,
                              hipStream_t stream) {
    const float* img = (const float*)d_in[0];   // (2048, 1024) fp32
    const float* U   = (const float*)d_in[1];   // (1024, 1024) fp32
    float* out = (float*)d_out;                 // (2048, 1024) fp32

    char* ws = (char*)d_ws;
    auto MB = [](size_t m) { return m << 20; };
    u16*   Uh  = (u16*)(ws + MB(0));
    u16*   Ul  = (u16*)(ws + MB(2));
    u16*   Uth = (u16*)(ws + MB(4));
    u16*   Utl = (u16*)(ws + MB(6));
    u16*   Wh  = (u16*)(ws + MB(8));
    u16*   Wl  = (u16*)(ws + MB(10));
    float* Csc = (float*)(ws + MB(12));          // 8 MB
    u16*   Rah = (u16*)(ws + MB(20));
    u16*   Ral = (u16*)(ws + MB(24));
    u16*   Rbh = (u16*)(ws + MB(28));
    u16*   Rbl = (u16*)(ws + MB(32));            // ends at 36 MB
    float* P   = (float*)(ws + MB(36));          // 24 MB split-K partials
    u32*   flg = (u32*)(ws + MB(60));            // 150*128 u32 = 76.8 KB
    u16*   Ih  = Rbh;   // img split lives only until Csc is built
    u16*   Il  = Rbl;

    const bool fast = ws_size >= (size_t)61 * 1024 * 1024;

    // ---- prologue ----
    k_split<<<4096, 256, 0, stream>>>(U, Uh, Ul, 1024 * 1024);
    k_split<<<8192, 256, 0, stream>>>(img, Ih, Il, 2048 * 1024);
    k_transpose_split<<<dim3(32, 32), 256, 0, stream>>>(U, Uth, Utl);

    // W = I - 0.2 * U @ U^T
    gemm_ista<2><<<128, 512, 0, stream>>>(Uh, Ul, Uh, Ul, 16,
                                          nullptr, nullptr, Wh, Wl);
    // Csc = 0.2 * img @ U^T ; R1 = st(Csc)
    gemm_ista<1><<<256, 512, 0, stream>>>(Ih, Il, Uh, Ul, 16,
                                          nullptr, Csc, Rah, Ral);

    u16 *ch = Rah, *cl = Ral, *nh = Rbh, *nl = Rbl;

    if (fast) {
        hipMemsetAsync(flg, 0, 150 * 128 * sizeof(u32), stream);
        // iterations 2..150: R <- st(R @ W + Csc), fused split-K combine
        for (int it = 0; it < 149; ++it) {
            gemm_it<0><<<512, 256, 0, stream>>>(Wh, Wl, ch, cl, Csc,
                                                nh, nl, nullptr,
                                                P, flg + it * 128, it & 3);
            u16* t;
            t = ch; ch = nh; nh = t;
            t = cl; cl = nl; nl = t;
        }
        // out = R @ U  (NT against Ut)
        gemm_it<1><<<512, 256, 0, stream>>>(Uth, Utl, ch, cl, nullptr,
                                            nullptr, nullptr, out,
                                            P, flg + 149 * 128, 149 & 3);
    } else {
        // fallback: round-5 path (no partial/flag workspace required)
        for (int it = 0; it < 149; ++it) {
            gemm_ista<3><<<256, 512, 0, stream>>>(ch, cl, Wh, Wl, 16,
                                                  Csc, nullptr, nh, nl);
            u16* t;
            t = ch; ch = nh; nh = t;
            t = cl; cl = nl; nl = t;
        }
        gemm_ista<0><<<256, 512, 0, stream>>>(ch, cl, Uth, Utl, 16,
                                              nullptr, out, nullptr, nullptr);
    }
}

// Round 8
// 5140.569 us; speedup vs baseline: 3.5105x; 1.8246x over previous
//
#include <hip/hip_runtime.h>
#include <cstddef>
#include <cstdint>

using f32x4  = __attribute__((ext_vector_type(4))) float;
using bf16x8 = __attribute__((ext_vector_type(8))) short;
using u16x4  = __attribute__((ext_vector_type(4))) unsigned short;
typedef unsigned short u16;

#define LMDA 0.005f

__device__ __forceinline__ u16 f2bf(float f) {
    union { float f; uint32_t u; } v; v.f = f;
    return (u16)((v.u + 0x7FFFu + ((v.u >> 16) & 1u)) >> 16);
}
__device__ __forceinline__ float bf2f(u16 b) {
    union { uint32_t u; float f; } v; v.u = ((uint32_t)b) << 16;
    return v.f;
}
__device__ __forceinline__ void split2(float x, u16& h, u16& l) {
    h = f2bf(x); l = f2bf(x - bf2f(h));
}
__device__ __forceinline__ float sthr(float x) {
    float ax = fabsf(x) - LMDA;
    return ax > 0.0f ? copysignf(ax, x) : 0.0f;
}

// async 16B global -> LDS (HW writes lane l at ldsbase + l*16)
__device__ __forceinline__ void gload16(const u16* g, u16* l) {
    __builtin_amdgcn_global_load_lds(
        (const __attribute__((address_space(1))) unsigned int*)(const void*)g,
        (__attribute__((address_space(3))) unsigned int*)(void*)l, 16, 0, 0);
}

// ---------------------------------------------------------------------------
// ITERATION KERNEL: tile 64x64, FULL K=1024 per block (no split-K), fused
// ISTA epilogue. grid 512 = 32(tr) x 16(tc) -> 2 blocks/CU: the other
// resident block's compute hides our stage+barrier drain (m97's missing
// ingredient in rounds 4-7).
//   acc[m][n] = sum_k Rh*Wh + Rl*Wh + Rh*Wl   (NT, k-stride 1024 both)
// 256 thr = 4 waves (wr,wc), wavetile 32x32 = 2x2 frags of 16x16x32.
// Swapped operands mfma(W-frag, R-frag): D col(lane&15)=m-local,
// row(e)=n-local -> epilogue is f32x4 Cs load + u16x4 Nh/Nl stores.
// LDS 2 x 32KB fragment-ordered 1KB chunks (lane*16B matches global_load_lds
// linear dest, conflict-free ds_read_b128).
// Per step: vmcnt(0); barrier; stage(next buf); 16 ds_read + 24 MFMA.
// OM 0: R' = split(st(acc + Cs))  (ISTA step)
// OM 1: OutF = acc                (final out = R@U)
// ---------------------------------------------------------------------------
template<int OM>
__global__ __launch_bounds__(256, 2)
void gemm_step(const u16* __restrict__ Rh, const u16* __restrict__ Rl,
               const u16* __restrict__ Wh, const u16* __restrict__ Wl,
               const float* __restrict__ Cs,
               u16* __restrict__ Nh, u16* __restrict__ Nl,
               float* __restrict__ OutF)
{
    __shared__ __align__(16) u16 S[2][32 * 512];   // 2 x 32 KiB

    // XCD-aware bijective swizzle (512 % 8 == 0). Per-XCD: 64 consecutive
    // tiles = 4 full tile-rows -> W fully L2-resident, 4 R-slabs hot.
    const int fid = blockIdx.x;
    const int sid = (fid & 7) * 64 + (fid >> 3);
    const int tr = sid >> 4;              // 0..31
    const int tc = sid & 15;              // 0..15
    const int row0 = tr << 6;
    const int col0 = tc << 6;

    const int tid  = threadIdx.x;
    const int lane = tid & 63;
    const int w    = tid >> 6;            // 0..3
    const int wr   = w >> 1;              // m-half of tile
    const int wc   = w & 1;               // n-half of tile
    const int l15  = lane & 15;
    const int lg   = lane >> 4;           // 0..3
    const int l8   = lane << 3;           // u16 offset of lane's 16B

    // ---- staging: 32 chunks of 1KB (16 R + 16 W), 8 per wave ----
    // chunk c: mat=c>>4 (0:R 1:W), within: h=(c>>3)&1, kh=(c>>2)&1, g=c&3
    // lane l <- M_h[base + g*16 + (l&15)][k0 + kh*32 + (l>>4)*8 .. +8)
    const u16* gsrc[8];
    int loff[8];
    #pragma unroll
    for (int t = 0; t < 8; ++t) {
        const int c  = (w << 3) + t;
        const int h  = (c >> 3) & 1;
        const int kh = (c >> 2) & 1;
        const int g  = c & 3;
        const u16* base;
        int r;
        if (c < 16) { base = h ? Rl : Rh; r = row0 + (g << 4) + l15; }
        else        { base = h ? Wl : Wh; r = col0 + (g << 4) + l15; }
        gsrc[t] = base + ((size_t)r << 10) + (kh << 5) + (lg << 3);
        loff[t] = (c << 9) + l8;
    }
    auto stage = [&](int b, int k) {
        #pragma unroll
        for (int t = 0; t < 8; ++t)
            gload16(gsrc[t] + k, &S[b][loff[t]]);
    };

    f32x4 acc[2][2] = {};   // [mf][nf]

    stage(0, 0);

    for (int s = 0; s < 16; ++s) {
        asm volatile("s_waitcnt vmcnt(0)" ::: "memory");
        __builtin_amdgcn_s_barrier();
        asm volatile("" ::: "memory");
        if (s < 15) stage((s + 1) & 1, (s + 1) << 6);

        const u16* Sb = S[s & 1];
        // frags: R chunk (h<<3)|(kh<<2)|(wr*2+mf) ; W chunk 16 + ...|(wc*2+nf)
        bf16x8 rh[2][2], rl[2][2], wh[2][2], wl[2][2];
        #pragma unroll
        for (int mf = 0; mf < 2; ++mf)
            #pragma unroll
            for (int kh = 0; kh < 2; ++kh) {
                const int g = (wr << 1) + mf;
                rh[mf][kh] = *(const bf16x8*)&Sb[(((0 << 3) | (kh << 2) | g) << 9) + l8];
                rl[mf][kh] = *(const bf16x8*)&Sb[(((1 << 3) | (kh << 2) | g) << 9) + l8];
            }
        #pragma unroll
        for (int nf = 0; nf < 2; ++nf)
            #pragma unroll
            for (int kh = 0; kh < 2; ++kh) {
                const int g = (wc << 1) + nf;
                wh[nf][kh] = *(const bf16x8*)&Sb[((16 + ((0 << 3) | (kh << 2) | g)) << 9) + l8];
                wl[nf][kh] = *(const bf16x8*)&Sb[((16 + ((1 << 3) | (kh << 2) | g)) << 9) + l8];
            }
        #pragma unroll
        for (int kh = 0; kh < 2; ++kh)
            #pragma unroll
            for (int mf = 0; mf < 2; ++mf)
                #pragma unroll
                for (int nf = 0; nf < 2; ++nf) {
                    acc[mf][nf] = __builtin_amdgcn_mfma_f32_16x16x32_bf16(wh[nf][kh], rh[mf][kh], acc[mf][nf], 0, 0, 0);
                    acc[mf][nf] = __builtin_amdgcn_mfma_f32_16x16x32_bf16(wh[nf][kh], rl[mf][kh], acc[mf][nf], 0, 0, 0);
                    acc[mf][nf] = __builtin_amdgcn_mfma_f32_16x16x32_bf16(wl[nf][kh], rh[mf][kh], acc[mf][nf], 0, 0, 0);
                }
        asm volatile("" ::: "memory");
    }

    // ---- fused epilogue (swapped-operand D layout: col=m-local, row=n-local)
    #pragma unroll
    for (int mf = 0; mf < 2; ++mf) {
        #pragma unroll
        for (int nf = 0; nf < 2; ++nf) {
            const int m  = row0 + (wr << 5) + (mf << 4) + l15;
            const int n0 = col0 + (wc << 5) + (nf << 4) + (lg << 2);
            const size_t idx = ((size_t)m << 10) + n0;
            if (OM == 0) {
                const f32x4 cs = *(const f32x4*)&Cs[idx];
                u16x4 hv, lv;
                #pragma unroll
                for (int e = 0; e < 4; ++e) {
                    u16 hh, ll; split2(sthr(acc[mf][nf][e] + cs[e]), hh, ll);
                    hv[e] = hh; lv[e] = ll;
                }
                *(u16x4*)&Nh[idx] = hv;
                *(u16x4*)&Nl[idx] = lv;
            } else {
                *(f32x4*)&OutF[idx] = acc[mf][nf];
            }
        }
    }
}

// ---------------------------------------------------------------------------
// PROLOGUE GEMM (round-5, passing): fused-3 split-bf16 NT GEMM + epilogues.
// EPI 1: OutF = 0.2*acc ; R = split(st(OutF))   (Csc and R1)
// EPI 2: OutH/L = split(I - 0.2*acc)            (W)
// ---------------------------------------------------------------------------
template<int EPI>
__global__ __launch_bounds__(512, 2)
void gemm_ista(const u16* __restrict__ Ah, const u16* __restrict__ Al,
               const u16* __restrict__ Bh, const u16* __restrict__ Bl,
               int Nt,
               const float* __restrict__ Cs, float* __restrict__ OutF,
               u16* __restrict__ OutH, u16* __restrict__ OutL)
{
    __shared__ __align__(16) u16 S[3][48 * 512];   // 144 KiB

    const int nwg = gridDim.x;
    const int fid = blockIdx.x;
    const int sid = (fid & 7) * (nwg >> 3) + (fid >> 3);
    const int row0 = (sid / Nt) << 7;
    const int col0 = (sid % Nt) << 6;

    const int tid  = threadIdx.x;
    const int lane = tid & 63;
    const int w    = tid >> 6;
    const int mr = w >> 2, nc = (w >> 1) & 1, ks = w & 1;

    const u16* gb[6];
    int cf[6];
    #pragma unroll
    for (int t = 0; t < 6; ++t) {
        const int c = w * 6 + t;
        const u16* base; int r; int kss;
        if (c < 32) {
            const int h = (c >> 4) & 1; kss = (c >> 3) & 1;
            base = h ? Al : Ah;
            r = row0 + ((c & 7) << 4) + (lane & 15);
        } else {
            const int cb = c - 32;
            const int h = (cb >> 3) & 1; kss = (cb >> 2) & 1;
            base = h ? Bl : Bh;
            r = col0 + ((cb & 3) << 4) + (lane & 15);
        }
        gb[t] = base + ((size_t)r << 10) + (kss << 5) + ((lane >> 4) << 3);
        cf[t] = c << 9;
    }
    auto stage = [&](int b, int koff) {
        #pragma unroll
        for (int t = 0; t < 6; ++t)
            gload16(gb[t] + koff, &S[b][cf[t]]);
    };

    f32x4 acc[4][2] = {};

    stage(0, 0);
    stage(1, 64);

    #pragma unroll
    for (int s = 0; s < 16; ++s) {
        if (s <= 14) asm volatile("s_waitcnt vmcnt(6)" ::: "memory");
        else         asm volatile("s_waitcnt vmcnt(0)" ::: "memory");
        __builtin_amdgcn_s_barrier();
        asm volatile("" ::: "memory");
        if (s + 2 < 16) stage((s + 2) % 3, (s + 2) << 6);

        const u16* Sb = S[s % 3];
        const int ab = (ks << 3) + (mr << 2);
        const int bb = 32 + (ks << 2) + (nc << 1);
        bf16x8 ah[4], al[4], bh[2], bl[2];
        #pragma unroll
        for (int i = 0; i < 4; ++i) {
            ah[i] = *(const bf16x8*)&Sb[(ab + i)      * 512 + (lane << 3)];
            al[i] = *(const bf16x8*)&Sb[(ab + 16 + i) * 512 + (lane << 3)];
        }
        #pragma unroll
        for (int j = 0; j < 2; ++j) {
            bh[j] = *(const bf16x8*)&Sb[(bb + j)     * 512 + (lane << 3)];
            bl[j] = *(const bf16x8*)&Sb[(bb + 8 + j) * 512 + (lane << 3)];
        }
        #pragma unroll
        for (int i = 0; i < 4; ++i)
            #pragma unroll
            for (int j = 0; j < 2; ++j)
                acc[i][j] = __builtin_amdgcn_mfma_f32_16x16x32_bf16(ah[i], bh[j], acc[i][j], 0, 0, 0);
        #pragma unroll
        for (int i = 0; i < 4; ++i)
            #pragma unroll
            for (int j = 0; j < 2; ++j)
                acc[i][j] = __builtin_amdgcn_mfma_f32_16x16x32_bf16(al[i], bh[j], acc[i][j], 0, 0, 0);
        #pragma unroll
        for (int i = 0; i < 4; ++i)
            #pragma unroll
            for (int j = 0; j < 2; ++j)
                acc[i][j] = __builtin_amdgcn_mfma_f32_16x16x32_bf16(ah[i], bl[j], acc[i][j], 0, 0, 0);
        asm volatile("" ::: "memory");
    }

    __syncthreads();
    f32x4* red = (f32x4*)&S[0][0];
    const int wquad = (mr << 1) + nc;
    #pragma unroll
    for (int ih = 0; ih < 2; ++ih) {
        #pragma unroll
        for (int j = 0; j < 2; ++j) {
            const int isrc = ks ? ih : (2 + ih);
            const int slot = ((((wquad << 1) | ks) << 2) | (ih << 1) | j);
            red[slot * 64 + lane] = acc[isrc][j];
        }
    }
    __syncthreads();

    const int gr0 = row0 + (mr << 6) + ((lane >> 4) << 2);
    const int gc  = col0 + (nc << 5) + (lane & 15);
    #pragma unroll
    for (int ih = 0; ih < 2; ++ih) {
        #pragma unroll
        for (int j = 0; j < 2; ++j) {
            const int i    = ks ? (2 + ih) : ih;
            const int slot = ((((wquad << 1) | (ks ^ 1)) << 2) | (ih << 1) | j);
            f32x4 sum = acc[i][j] + red[slot * 64 + lane];
            #pragma unroll
            for (int e = 0; e < 4; ++e) {
                const int grow = gr0 + (i << 4) + e;
                const int gcol = gc + (j << 4);
                const size_t idx = ((size_t)grow << 10) + gcol;
                const float p = sum[e];
                if (EPI == 1) {
                    float f = 0.2f * p;
                    OutF[idx] = f;
                    u16 h, l; split2(sthr(f), h, l);
                    OutH[idx] = h; OutL[idx] = l;
                } else {
                    float x = (grow == gcol ? 1.0f : 0.0f) - 0.2f * p;
                    u16 h, l; split2(x, h, l);
                    OutH[idx] = h; OutL[idx] = l;
                }
            }
        }
    }
}

// fp32 -> (hi, lo) bf16 pair, elementwise
__global__ void k_split(const float* __restrict__ in, u16* __restrict__ hi,
                        u16* __restrict__ lo, int n)
{
    int i = blockIdx.x * 256 + threadIdx.x;
    if (i < n) { u16 h, l; split2(in[i], h, l); hi[i] = h; lo[i] = l; }
}

// Ut[j][k] = U[k][j] as bf16 pair (32x32 LDS tile, padded)
__global__ __launch_bounds__(256)
void k_transpose_split(const float* __restrict__ in, u16* __restrict__ hi,
                       u16* __restrict__ lo)
{
    __shared__ float t[32][33];
    const int bx = blockIdx.x, by = blockIdx.y;
    const int lx = threadIdx.x & 31, ly = threadIdx.x >> 5;
    #pragma unroll
    for (int rr = 0; rr < 4; ++rr) {
        int r = ly * 4 + rr;
        t[r][lx] = in[(size_t)(by * 32 + r) * 1024 + bx * 32 + lx];
    }
    __syncthreads();
    #pragma unroll
    for (int rr = 0; rr < 4; ++rr) {
        int r = ly * 4 + rr;
        u16 h, l; split2(t[lx][r], h, l);
        size_t idx = (size_t)(bx * 32 + r) * 1024 + by * 32 + lx;
        hi[idx] = h; lo[idx] = l;
    }
}

extern "C" void kernel_launch(void* const* d_in, const int* in_sizes, int n_in,
                              void* d_out, int out_size, void* d_ws, size_t ws_size,
                              hipStream_t stream) {
    const float* img = (const float*)d_in[0];   // (2048, 1024) fp32
    const float* U   = (const float*)d_in[1];   // (1024, 1024) fp32
    float* out = (float*)d_out;                 // (2048, 1024) fp32

    char* ws = (char*)d_ws;
    auto MB = [](size_t m) { return m << 20; };
    u16*   Uh  = (u16*)(ws + MB(0));
    u16*   Ul  = (u16*)(ws + MB(2));
    u16*   Uth = (u16*)(ws + MB(4));
    u16*   Utl = (u16*)(ws + MB(6));
    u16*   Wh  = (u16*)(ws + MB(8));
    u16*   Wl  = (u16*)(ws + MB(10));
    float* Csc = (float*)(ws + MB(12));          // 8 MB
    u16*   Rah = (u16*)(ws + MB(20));
    u16*   Ral = (u16*)(ws + MB(24));
    u16*   Rbh = (u16*)(ws + MB(28));
    u16*   Rbl = (u16*)(ws + MB(32));            // ends at 36 MB
    u16*   Ih  = Rbh;   // img split lives only until Csc is built
    u16*   Il  = Rbl;

    // ---- prologue ----
    k_split<<<4096, 256, 0, stream>>>(U, Uh, Ul, 1024 * 1024);
    k_split<<<8192, 256, 0, stream>>>(img, Ih, Il, 2048 * 1024);
    k_transpose_split<<<dim3(32, 32), 256, 0, stream>>>(U, Uth, Utl);

    // W = I - 0.2 * U @ U^T
    gemm_ista<2><<<128, 512, 0, stream>>>(Uh, Ul, Uh, Ul, 16,
                                          nullptr, nullptr, Wh, Wl);
    // Csc = 0.2 * img @ U^T ; R1 = st(Csc)
    gemm_ista<1><<<256, 512, 0, stream>>>(Ih, Il, Uh, Ul, 16,
                                          nullptr, Csc, Rah, Ral);

    // ---- iterations 2..150: R <- st(R @ W + Csc), 512 blocks, 2/CU ----
    u16 *ch = Rah, *cl = Ral, *nh = Rbh, *nl = Rbl;
    for (int it = 0; it < 149; ++it) {
        gemm_step<0><<<512, 256, 0, stream>>>(ch, cl, Wh, Wl, Csc,
                                              nh, nl, nullptr);
        u16* t;
        t = ch; ch = nh; nh = t;
        t = cl; cl = nl; nl = t;
    }

    // ---- out = R @ U (NT against Ut) ----
    gemm_step<1><<<512, 256, 0, stream>>>(ch, cl, Uth, Utl, nullptr,
                                          nullptr, nullptr, out);
}